// Round 8
// baseline (348.294 us; speedup 1.0000x reference)
//
#include <hip/hip_runtime.h>
#include <stdint.h>

#define B_ 2
#define S_ 2048
#define DIM_ 2048
#define H_ 16
#define KVH_ 4
#define HD_ 128

typedef short short8 __attribute__((ext_vector_type(8)));
typedef float f4 __attribute__((ext_vector_type(4)));
typedef unsigned short u16;

// softmax scale folded into Q: 1/sqrt(128) * log2(e)
#define KSCALE (0.08838834764831845f * 1.4426950408889634f)

__device__ __forceinline__ float bf2f(u16 u) {
    union { unsigned int i; float f; } c; c.i = ((unsigned int)u) << 16; return c.f;
}
__device__ __forceinline__ u16 f2bf(float f) {
    union { float f; unsigned int i; } c; c.f = f;
    return (u16)((c.i + 0x7fffu + ((c.i >> 16) & 1u)) >> 16);
}

// async global->LDS, 16B per lane; LDS dest is wave-uniform base + lane*16
#define GLDS16(gp, lp) \
    __builtin_amdgcn_global_load_lds((const __attribute__((address_space(1))) unsigned int*)(gp), \
                                     (__attribute__((address_space(3))) unsigned int*)(lp), 16, 0, 0)

// ---------------- fused fp32 -> bf16 cast of all 5 tensors ----------------
__global__ void cast_all(const float* __restrict__ x,  const float* __restrict__ wq,
                         const float* __restrict__ wk, const float* __restrict__ wv,
                         const float* __restrict__ wo,
                         u16* __restrict__ xb, u16* __restrict__ wqkvb, u16* __restrict__ wob) {
    int i = blockIdx.x * 256 + threadIdx.x;   // float4 index, total 4718592
    const float4* src; ushort4* dst; int j;
    if (i < 2097152)      { src = (const float4*)x;  dst = (ushort4*)xb;                 j = i; }
    else if (i < 3145728) { src = (const float4*)wq; dst = (ushort4*)wqkvb;              j = i - 2097152; }
    else if (i < 3407872) { src = (const float4*)wk; dst = (ushort4*)wqkvb + 1048576;    j = i - 3145728; }
    else if (i < 3670016) { src = (const float4*)wv; dst = (ushort4*)wqkvb + 1310720;    j = i - 3407872; }
    else                  { src = (const float4*)wo; dst = (ushort4*)wob;                j = i - 3670016; }
    float4 v = src[j];
    ushort4 o;
    o.x = f2bf(v.x); o.y = f2bf(v.y); o.z = f2bf(v.z); o.w = f2bf(v.w);
    dst[j] = o;
}

// ---------------- generic GEMM (used for O-projection): C = A @ W^T ----------------
template<bool OUT_BF16>
__global__ __launch_bounds__(256) void gemm_bt(const u16* __restrict__ A,
                                               const u16* __restrict__ W,
                                               void* __restrict__ Cout,
                                               int M, int N, int K) {
    __shared__ u16 As[128 * 32];
    __shared__ u16 Bs[128 * 32];
    int t = threadIdx.x, lane = t & 63, w = t >> 6;
    int quad = lane >> 4, l16 = lane & 15;
    int wm = w & 1, wn = w >> 1;
    size_t m0 = (size_t)blockIdx.y * 128, n0 = (size_t)blockIdx.x * 128;

    int c0 = w * 2;
    int ar = c0 * 16 + (lane >> 2);
    int ac = (lane & 3) * 8;
    const u16* Abase = A + (m0 + ar) * (size_t)K + ac;
    const u16* Bbase = W + (n0 + ar) * (size_t)K + ac;
    u16* Adst = As + c0 * 512;
    u16* Bdst = Bs + c0 * 512;

    f4 acc[4][4];
    #pragma unroll
    for (int i = 0; i < 4; i++)
        #pragma unroll
        for (int j = 0; j < 4; j++) acc[i][j] = (f4){0.f, 0.f, 0.f, 0.f};

    int nk = K >> 5;
    for (int kt = 0; kt < nk; kt++) {
        const u16* ga = Abase + kt * 32;
        const u16* gb = Bbase + kt * 32;
        GLDS16(ga, Adst);
        GLDS16(ga + 16 * (size_t)K, Adst + 512);
        GLDS16(gb, Bdst);
        GLDS16(gb + 16 * (size_t)K, Bdst + 512);
        __syncthreads();
        short8 a[4], b[4];
        #pragma unroll
        for (int i = 0; i < 4; i++) a[i] = *(const short8*)&As[(wm * 64 + i * 16 + l16) * 32 + quad * 8];
        #pragma unroll
        for (int j = 0; j < 4; j++) b[j] = *(const short8*)&Bs[(wn * 64 + j * 16 + l16) * 32 + quad * 8];
        #pragma unroll
        for (int i = 0; i < 4; i++)
            #pragma unroll
            for (int j = 0; j < 4; j++)
                acc[i][j] = __builtin_amdgcn_mfma_f32_16x16x32_bf16(a[i], b[j], acc[i][j], 0, 0, 0);
        __syncthreads();
    }
    #pragma unroll
    for (int i = 0; i < 4; i++) {
        size_t row = m0 + wm * 64 + i * 16 + quad * 4;
        #pragma unroll
        for (int j = 0; j < 4; j++) {
            size_t col = n0 + wn * 64 + j * 16 + l16;
            #pragma unroll
            for (int r = 0; r < 4; r++) {
                if (OUT_BF16) ((u16*)Cout)[(row + r) * N + col] = f2bf(acc[i][j][r]);
                else          ((float*)Cout)[(row + r) * N + col] = acc[i][j][r];
            }
        }
    }
}

// ---------------- QKV GEMM with fused RoPE + fragment packing ----------------
// M=4096, N=3072, K=2048. Block cols: bx<16 -> Q (+RoPE+KSCALE -> Qb[4096][2048]),
// bx 16..19 -> K (+RoPE -> packed Kp), bx 20..23 -> V (-> packed Vp).
// RoPE pairs (even,odd hd) live in adjacent l16 lanes -> shfl_xor(1) exchange.
__global__ __launch_bounds__(256) void gemm_qkv(const u16* __restrict__ A,
                                                const u16* __restrict__ W,
                                                const float* __restrict__ freqs,
                                                u16* __restrict__ Qb,
                                                u16* __restrict__ Kp,
                                                u16* __restrict__ Vp) {
    __shared__ u16 As[128 * 32];
    __shared__ u16 Bs[128 * 32];
    const int K = 2048;
    int t = threadIdx.x, lane = t & 63, w = t >> 6;
    int quad = lane >> 4, l16 = lane & 15;
    int wm = w & 1, wn = w >> 1;
    int bx = blockIdx.x;
    size_t m0 = (size_t)blockIdx.y * 128, n0 = (size_t)bx * 128;

    int c0 = w * 2;
    int ar = c0 * 16 + (lane >> 2);
    int ac = (lane & 3) * 8;
    const u16* Abase = A + (m0 + ar) * (size_t)K + ac;
    const u16* Bbase = W + (n0 + ar) * (size_t)K + ac;
    u16* Adst = As + c0 * 512;
    u16* Bdst = Bs + c0 * 512;

    f4 acc[4][4];
    #pragma unroll
    for (int i = 0; i < 4; i++)
        #pragma unroll
        for (int j = 0; j < 4; j++) acc[i][j] = (f4){0.f, 0.f, 0.f, 0.f};

    for (int kt = 0; kt < 64; kt++) {
        const u16* ga = Abase + kt * 32;
        const u16* gb = Bbase + kt * 32;
        GLDS16(ga, Adst);
        GLDS16(ga + 16 * (size_t)K, Adst + 512);
        GLDS16(gb, Bdst);
        GLDS16(gb + 16 * (size_t)K, Bdst + 512);
        __syncthreads();
        short8 a[4], b[4];
        #pragma unroll
        for (int i = 0; i < 4; i++) a[i] = *(const short8*)&As[(wm * 64 + i * 16 + l16) * 32 + quad * 8];
        #pragma unroll
        for (int j = 0; j < 4; j++) b[j] = *(const short8*)&Bs[(wn * 64 + j * 16 + l16) * 32 + quad * 8];
        #pragma unroll
        for (int i = 0; i < 4; i++)
            #pragma unroll
            for (int j = 0; j < 4; j++)
                acc[i][j] = __builtin_amdgcn_mfma_f32_16x16x32_bf16(a[i], b[j], acc[i][j], 0, 0, 0);
        __syncthreads();
    }

    const float2* fr2 = (const float2*)freqs;
    if (bx < 16) {
        // ---- Q: RoPE + KSCALE -> Qb ----
        #pragma unroll
        for (int i = 0; i < 4; i++) {
            #pragma unroll
            for (int j = 0; j < 4; j++) {
                #pragma unroll
                for (int r = 0; r < 4; r++) {
                    int row = (int)m0 + wm * 64 + i * 16 + quad * 4 + r;
                    int col = (int)n0 + wn * 64 + j * 16 + l16;
                    float v = acc[i][j][r];
                    float pv = __shfl_xor(v, 1, 64);
                    int s = row & 2047;
                    float2 cs = fr2[s * 64 + ((col & 127) >> 1)];
                    float rot = (l16 & 1) ? (pv * cs.y + v * cs.x) : (v * cs.x - pv * cs.y);
                    Qb[(size_t)row * 2048 + col] = f2bf(rot * KSCALE);
                }
            }
        }
    } else if (bx < 20) {
        // ---- K: RoPE -> packed Kp[bk][kt][n*4+c][quadk*16+l16k][jk] ----
        int kvh = bx - 16;
        #pragma unroll
        for (int i = 0; i < 4; i++) {
            #pragma unroll
            for (int j = 0; j < 4; j++) {
                #pragma unroll
                for (int r = 0; r < 4; r++) {
                    int row = (int)m0 + wm * 64 + i * 16 + quad * 4 + r;
                    int hd = wn * 64 + j * 16 + l16;
                    float v = acc[i][j][r];
                    float pv = __shfl_xor(v, 1, 64);
                    int s = row & 2047, bb = row >> 11;
                    float2 cs = fr2[s * 64 + (hd >> 1)];
                    float rot = (l16 & 1) ? (pv * cs.y + v * cs.x) : (v * cs.x - pv * cs.y);
                    int bk2 = bb * 4 + kvh, kt2 = s >> 6, s6 = s & 63;
                    int idx = (((bk2 * 32 + kt2) * 16) + ((s6 >> 4) * 4 + (hd >> 5))) * 512
                              + (((hd >> 3) & 3) * 16 + (s6 & 15)) * 8 + (hd & 7);
                    Kp[idx] = f2bf(rot);
                }
            }
        }
    } else {
        // ---- V -> packed Vp[bk][kt][nt*2+kc][quadv*16+l16v][jv] ----
        int kvh = bx - 20;
        #pragma unroll
        for (int i = 0; i < 4; i++) {
            #pragma unroll
            for (int j = 0; j < 4; j++) {
                #pragma unroll
                for (int r = 0; r < 4; r++) {
                    int row = (int)m0 + wm * 64 + i * 16 + quad * 4 + r;
                    int hd = wn * 64 + j * 16 + l16;
                    int s = row & 2047, bb = row >> 11;
                    int bk2 = bb * 4 + kvh, kt2 = s >> 6, s6 = s & 63;
                    int idx = (((bk2 * 32 + kt2) * 16) + ((hd >> 4) * 2 + (s6 >> 5))) * 512
                              + (((s6 >> 3) & 3) * 16 + (hd & 15)) * 8 + (s6 & 7);
                    Vp[idx] = f2bf(acc[i][j][r]);
                }
            }
        }
    }
}

// ---------------- Flash attention ----------------
// block = (bk, pr, half): 1024 blocks, uniform work. Waves 0,1 = heads half*2+{0,1}
// at q-tile 127-pr; waves 2,3 = same heads at q-tile pr. One staged K/V tile serves
// all 4 waves; waves past their nkt idle at barriers. LDS 36KB -> 4 blocks/CU = 16
// waves/CU. waves_per_eu(4,4) caps VGPR at 128 (body needs ~96, no spill).
__global__ __launch_bounds__(256) __attribute__((amdgpu_waves_per_eu(4, 4)))
void attn_kernel(const u16* __restrict__ Qb,
                 const u16* __restrict__ Kp,
                 const u16* __restrict__ Vp,
                 u16* __restrict__ Ob) {
    __shared__ u16 Ks[16 * 512];   // 16KB packed K tile
    __shared__ u16 Vs[16 * 512];   // 16KB packed V tile
    __shared__ u16 Ps[4 * 1024];   // 4KB: per-wave P (16x64), XOR-swizzled
    int bid = blockIdx.x;          // 1024 blocks
    int bk = bid & 7, pr = (bid >> 3) & 63, half = bid >> 9;
    int b = bk >> 2, kvh = bk & 3;
    int t = threadIdx.x, lane = t & 63, w = t >> 6, quad = lane >> 4, l16 = lane & 15;
    int l7 = l16 & 7, hi = l16 >> 3;
    int h = kvh * 4 + half * 2 + (w & 1);
    int qt = (w < 2) ? (127 - pr) : pr;
    int nkt = (qt >> 2) + 1;
    int nktL = 32 - (pr >> 2);     // = ((127-pr)>>2)+1, wave-uniform loop bound

    short8 ones;
    #pragma unroll
    for (int j = 0; j < 8; j++) ones[j] = (short)0x3F80;

    // Q fragments (A-layout, pre-scaled by KSCALE in gemm_qkv epilogue)
    short8 qf[4];
    {
        const u16* qp = Qb + ((size_t)(b * S_ + qt * 16 + l16)) * 2048 + h * HD_ + quad * 8;
        #pragma unroll
        for (int c = 0; c < 4; c++) qf[c] = *(const short8*)(qp + c * 32);
    }
    float m_i = -3e38f;
    f4 ls = (f4){0.f, 0.f, 0.f, 0.f};
    f4 o[8];
    #pragma unroll
    for (int n = 0; n < 8; n++) o[n] = (f4){0.f, 0.f, 0.f, 0.f};

    const u16* Kpb = Kp + (size_t)bk * 32 * 8192;
    const u16* Vpb = Vp + (size_t)bk * 32 * 8192;
    u16* P = Ps + w * 1024;

    for (int kt = 0; kt < nktL; kt++) {
        // stage packed K,V tiles: wave w stages fragments w*4..w*4+3 of each
        {
            const u16* ks = Kpb + (size_t)kt * 8192 + (w * 4) * 512 + lane * 8;
            const u16* vs = Vpb + (size_t)kt * 8192 + (w * 4) * 512 + lane * 8;
            #pragma unroll
            for (int i = 0; i < 4; i++) {
                GLDS16(ks + i * 512, &Ks[(w * 4 + i) * 512]);
                GLDS16(vs + i * 512, &Vs[(w * 4 + i) * 512]);
            }
        }
        __syncthreads();

        if (kt < nkt) {   // wave-uniform activity guard
            // QK^T (Q pre-scaled -> scores already in log2 domain)
            f4 sc[4];
            #pragma unroll
            for (int n = 0; n < 4; n++) sc[n] = (f4){0.f, 0.f, 0.f, 0.f};
            #pragma unroll
            for (int n = 0; n < 4; n++) {
                #pragma unroll
                for (int c = 0; c < 4; c++) {
                    short8 kf = *(const short8*)&Ks[(n * 4 + c) * 512 + lane * 8];
                    sc[n] = __builtin_amdgcn_mfma_f32_16x16x32_bf16(qf[c], kf, sc[n], 0, 0, 0);
                }
            }
            // causal mask only on the diagonal k-tile
            if (kt == nkt - 1) {
                int qrow0 = qt * 16 + quad * 4;
                #pragma unroll
                for (int n = 0; n < 4; n++) {
                    int colg = kt * 64 + n * 16 + l16;
                    #pragma unroll
                    for (int r = 0; r < 4; r++)
                        sc[n][r] = (colg <= qrow0 + r) ? sc[n][r] : -3e38f;
                }
            }
            // wave-group max (one scalar m per wave; exact — any per-row constant works)
            float gm = fmaxf(fmaxf(sc[0][0], sc[0][1]), fmaxf(sc[0][2], sc[0][3]));
            #pragma unroll
            for (int n = 1; n < 4; n++)
                gm = fmaxf(gm, fmaxf(fmaxf(sc[n][0], sc[n][1]), fmaxf(sc[n][2], sc[n][3])));
            #pragma unroll
            for (int off = 1; off < 64; off <<= 1) gm = fmaxf(gm, __shfl_xor(gm, off, 64));
            float mnew = fmaxf(m_i, gm);
            if (mnew > m_i) {              // wave-uniform branch
                float al = exp2f(m_i - mnew);
                m_i = mnew;
                #pragma unroll
                for (int r = 0; r < 4; r++) ls[r] *= al;
                #pragma unroll
                for (int nt = 0; nt < 8; nt++)
                    #pragma unroll
                    for (int r = 0; r < 4; r++) o[nt][r] *= al;
            }
            // P = exp2(s - m), truncate-pack to bf16, swizzled LDS write
            #pragma unroll
            for (int n = 0; n < 4; n++) {
                #pragma unroll
                for (int r = 0; r < 4; r++) {
                    float p = exp2f(sc[n][r] - m_i);
                    union { float f; unsigned int u; } cv; cv.f = p;
                    int row = quad * 4 + r;
                    int sw = (n * 2 + hi) ^ (row & 7);
                    P[row * 64 + sw * 8 + l7] = (u16)(cv.u >> 16);
                }
            }
            __asm__ volatile("s_waitcnt lgkmcnt(0)" ::: "memory");

            // PV: O += P @ V ; l += P @ ones (MFMA row-sum)
            #pragma unroll
            for (int kc = 0; kc < 2; kc++) {
                short8 af = *(const short8*)&P[l16 * 64 + (((kc * 4 + quad) ^ l7) << 3)];
                ls = __builtin_amdgcn_mfma_f32_16x16x32_bf16(af, ones, ls, 0, 0, 0);
                #pragma unroll
                for (int nt = 0; nt < 8; nt++) {
                    short8 vf = *(const short8*)&Vs[(nt * 2 + kc) * 512 + lane * 8];
                    o[nt] = __builtin_amdgcn_mfma_f32_16x16x32_bf16(af, vf, o[nt], 0, 0, 0);
                }
            }
        }
        __syncthreads();
    }
    // epilogue
    float rl[4];
    #pragma unroll
    for (int r = 0; r < 4; r++) rl[r] = 1.0f / ls[r];
    #pragma unroll
    for (int nt = 0; nt < 8; nt++)
        #pragma unroll
        for (int r = 0; r < 4; r++) {
            size_t row = (size_t)b * S_ + qt * 16 + quad * 4 + r;
            Ob[row * 2048 + h * HD_ + nt * 16 + l16] = f2bf(o[nt][r] * rl[r]);
        }
}

extern "C" void kernel_launch(void* const* d_in, const int* in_sizes, int n_in,
                              void* d_out, int out_size, void* d_ws, size_t ws_size,
                              hipStream_t stream) {
    const float* x     = (const float*)d_in[0];
    const float* freqs = (const float*)d_in[1];
    const float* wq    = (const float*)d_in[2];
    const float* wk    = (const float*)d_in[3];
    const float* wv    = (const float*)d_in[4];
    const float* wo    = (const float*)d_in[5];
    float* out = (float*)d_out;

    char* p = (char*)d_ws;
    u16* xb    = (u16*)p; p += (size_t)4096 * 2048 * 2;   // 16MB
    u16* wqkvb = (u16*)p; p += (size_t)3072 * 2048 * 2;   // 12MB
    u16* wob   = (u16*)p; p += (size_t)2048 * 2048 * 2;   // 8MB
    u16* Qb    = (u16*)p; p += (size_t)4096 * 2048 * 2;   // 16MB
    u16* Kpb   = (u16*)p; p += (size_t)8 * 32 * 8192 * 2; // 4MB
    u16* Vpb   = (u16*)p; p += (size_t)8 * 32 * 8192 * 2; // 4MB
    u16* attnb = xb;  // reuse: x not needed after gemm_qkv

    cast_all<<<18432, 256, 0, stream>>>(x, wq, wk, wv, wo, xb, wqkvb, wob);

    gemm_qkv<<<dim3(24, 32), 256, 0, stream>>>(xb, wqkvb, freqs, Qb, Kpb, Vpb);

    attn_kernel<<<1024, 256, 0, stream>>>(Qb, Kpb, Vpb, attnb);

    gemm_bt<false><<<dim3(16, 32), 256, 0, stream>>>(attnb, wob, out, 4096, 2048, 2048);
}

// Round 9
// 326.444 us; speedup vs baseline: 1.0669x; 1.0669x over previous
//
#include <hip/hip_runtime.h>
#include <stdint.h>

#define B_ 2
#define S_ 2048
#define DIM_ 2048
#define H_ 16
#define KVH_ 4
#define HD_ 128

typedef short short8 __attribute__((ext_vector_type(8)));
typedef float f4 __attribute__((ext_vector_type(4)));
typedef unsigned short u16;

// softmax scale folded into Q at attn load: 1/sqrt(128) * log2(e)
#define KSCALE (0.08838834764831845f * 1.4426950408889634f)

__device__ __forceinline__ float bf2f(u16 u) {
    union { unsigned int i; float f; } c; c.i = ((unsigned int)u) << 16; return c.f;
}
__device__ __forceinline__ u16 f2bf(float f) {
    union { float f; unsigned int i; } c; c.f = f;
    return (u16)((c.i + 0x7fffu + ((c.i >> 16) & 1u)) >> 16);
}

// async global->LDS, 16B per lane; LDS dest is wave-uniform base + lane*16
#define GLDS16(gp, lp) \
    __builtin_amdgcn_global_load_lds((const __attribute__((address_space(1))) unsigned int*)(gp), \
                                     (__attribute__((address_space(3))) unsigned int*)(lp), 16, 0, 0)

// ---------------- fused fp32 -> bf16 cast of all 5 tensors ----------------
__global__ void cast_all(const float* __restrict__ x,  const float* __restrict__ wq,
                         const float* __restrict__ wk, const float* __restrict__ wv,
                         const float* __restrict__ wo,
                         u16* __restrict__ xb, u16* __restrict__ wqkvb, u16* __restrict__ wob) {
    int i = blockIdx.x * 256 + threadIdx.x;   // float4 index, total 4718592
    const float4* src; ushort4* dst; int j;
    if (i < 2097152)      { src = (const float4*)x;  dst = (ushort4*)xb;                 j = i; }
    else if (i < 3145728) { src = (const float4*)wq; dst = (ushort4*)wqkvb;              j = i - 2097152; }
    else if (i < 3407872) { src = (const float4*)wk; dst = (ushort4*)wqkvb + 1048576;    j = i - 3145728; }
    else if (i < 3670016) { src = (const float4*)wv; dst = (ushort4*)wqkvb + 1310720;    j = i - 3407872; }
    else                  { src = (const float4*)wo; dst = (ushort4*)wob;                j = i - 3670016; }
    float4 v = src[j];
    ushort4 o;
    o.x = f2bf(v.x); o.y = f2bf(v.y); o.z = f2bf(v.z); o.w = f2bf(v.w);
    dst[j] = o;
}

// ---------------- GEMM: C[M,N] = A[M,K] @ W[N,K]^T, m97 structure ----------------
// 1D grid, XCD-swizzled: all NBX column-blocks of one row-tile share bid%8 (same XCD's
// L2 serves the A row-tile). NBY must be divisible by 8.
template<bool OUT_BF16, int NBX>
__global__ __launch_bounds__(256) void gemm_bt(const u16* __restrict__ A,
                                               const u16* __restrict__ W,
                                               void* __restrict__ Cout,
                                               int M, int N, int K) {
    __shared__ u16 As[128 * 32];
    __shared__ u16 Bs[128 * 32];
    int t = threadIdx.x, lane = t & 63, w = t >> 6;
    int quad = lane >> 4, l16 = lane & 15;
    int wm = w & 1, wn = w >> 1;
    int bid = blockIdx.x;
    int xcd = bid & 7, grp = bid >> 3;
    int bx = grp % NBX, by = (grp / NBX) * 8 + xcd;
    size_t m0 = (size_t)by * 128, n0 = (size_t)bx * 128;

    int c0 = w * 2;
    int ar = c0 * 16 + (lane >> 2);
    int ac = (lane & 3) * 8;
    const u16* Abase = A + (m0 + ar) * (size_t)K + ac;
    const u16* Bbase = W + (n0 + ar) * (size_t)K + ac;
    u16* Adst = As + c0 * 512;
    u16* Bdst = Bs + c0 * 512;

    f4 acc[4][4];
    #pragma unroll
    for (int i = 0; i < 4; i++)
        #pragma unroll
        for (int j = 0; j < 4; j++) acc[i][j] = (f4){0.f, 0.f, 0.f, 0.f};

    int nk = K >> 5;
    for (int kt = 0; kt < nk; kt++) {
        const u16* ga = Abase + kt * 32;
        const u16* gb = Bbase + kt * 32;
        GLDS16(ga, Adst);
        GLDS16(ga + 16 * (size_t)K, Adst + 512);
        GLDS16(gb, Bdst);
        GLDS16(gb + 16 * (size_t)K, Bdst + 512);
        __syncthreads();
        short8 a[4], b[4];
        #pragma unroll
        for (int i = 0; i < 4; i++) a[i] = *(const short8*)&As[(wm * 64 + i * 16 + l16) * 32 + quad * 8];
        #pragma unroll
        for (int j = 0; j < 4; j++) b[j] = *(const short8*)&Bs[(wn * 64 + j * 16 + l16) * 32 + quad * 8];
        #pragma unroll
        for (int i = 0; i < 4; i++)
            #pragma unroll
            for (int j = 0; j < 4; j++)
                acc[i][j] = __builtin_amdgcn_mfma_f32_16x16x32_bf16(a[i], b[j], acc[i][j], 0, 0, 0);
        __syncthreads();
    }
    #pragma unroll
    for (int i = 0; i < 4; i++) {
        size_t row = m0 + wm * 64 + i * 16 + quad * 4;
        #pragma unroll
        for (int j = 0; j < 4; j++) {
            size_t col = n0 + wn * 64 + j * 16 + l16;
            #pragma unroll
            for (int r = 0; r < 4; r++) {
                if (OUT_BF16) ((u16*)Cout)[(row + r) * N + col] = f2bf(acc[i][j][r]);
                else          ((float*)Cout)[(row + r) * N + col] = acc[i][j][r];
            }
        }
    }
}

// ---------------- pack K (with fused RoPE) into MFMA B-fragment order ----------------
// Kp[bk][kt][fid=n*4+c][lane][8] = rope(K)[b, s=kt*64+n*16+l16, kvh, hd=c*32+quad*8+j]
__global__ __launch_bounds__(256) void pack_k(const u16* __restrict__ QKV,
                                              const float* __restrict__ freqs,
                                              u16* __restrict__ Kp) {
    int gid = blockIdx.x * 256 + threadIdx.x;   // 262144
    int lane = gid & 63;
    int fid = (gid >> 6) & 15;
    int kt = (gid >> 10) & 31;
    int bk = gid >> 15;
    int b = bk >> 2, kvh = bk & 3;
    int n = fid >> 2, c = fid & 3;
    int l16 = lane & 15, quad = lane >> 4;
    int s = kt * 64 + n * 16 + l16;
    const u16* src = QKV + (size_t)(b * 2048 + s) * 3072 + 2048 + kvh * 128 + c * 32 + quad * 8;
    short8 v = *(const short8*)src;
    short8 o;
    #pragma unroll
    for (int jp = 0; jp < 4; jp++) {
        int hd2 = c * 16 + quad * 4 + jp;
        float2 cw = ((const float2*)freqs)[s * 64 + hd2];
        float x0 = bf2f((u16)v[2 * jp]), x1 = bf2f((u16)v[2 * jp + 1]);
        o[2 * jp]     = (short)f2bf(x0 * cw.x - x1 * cw.y);
        o[2 * jp + 1] = (short)f2bf(x0 * cw.y + x1 * cw.x);
    }
    *(short8*)&Kp[(size_t)gid * 8] = o;
}

// ---------------- pack V into MFMA B-fragment order (LDS-tile transpose) ----------------
// Vp[bk][kt][fid=nt*2+kc][lane][8] = V[b, s=kt*64+kc*32+quad*8+j, kvh, hd=nt*16+l16]
__global__ __launch_bounds__(256) void pack_v(const u16* __restrict__ QKV, u16* __restrict__ Vp) {
    __shared__ u16 L[64 * 136];
    int bid = blockIdx.x;          // 256 blocks
    int bk = bid & 7, kt = bid >> 3;
    int b = bk >> 2, kvh = bk & 3;
    int t = threadIdx.x;
    const u16* src = QKV + (size_t)(b * 2048 + kt * 64) * 3072 + 2560 + kvh * 128;
    #pragma unroll
    for (int it = 0; it < 4; it++) {
        int idx = t + it * 256;
        int r = idx >> 4, c = idx & 15;
        *(short8*)&L[r * 136 + c * 8] = *(const short8*)(src + (size_t)r * 3072 + c * 8);
    }
    __syncthreads();
    u16* dst = Vp + ((size_t)bk * 32 + kt) * 8192;
    #pragma unroll
    for (int it = 0; it < 4; it++) {
        int idx = t + it * 256;
        int fid = idx >> 6, lane = idx & 63;
        int nt = fid >> 1, kc = fid & 1;
        int l16 = lane & 15, quad = lane >> 4;
        int hd = nt * 16 + l16;
        int s0 = kc * 32 + quad * 8;
        short8 v;
        #pragma unroll
        for (int j = 0; j < 8; j++) v[j] = (short)L[(s0 + j) * 136 + hd];
        *(short8*)&dst[(size_t)idx * 8] = v;
    }
}

// ---------------- Flash attention (RoPE-Q fused at fragment load) ----------------
// block = (bk, pr, half): 1024 blocks, uniform work. Waves 0,1 = heads half*2+{0,1}
// at q-tile 127-pr; waves 2,3 = same heads at q-tile pr. One staged K/V tile serves
// all 4 waves. LDS 36KB -> 4 blocks/CU = 16 waves/CU. waves_per_eu(4,4) caps VGPR 128.
__global__ __launch_bounds__(256) __attribute__((amdgpu_waves_per_eu(4, 4)))
void attn_kernel(const u16* __restrict__ QKV,
                 const float* __restrict__ freqs,
                 const u16* __restrict__ Kp,
                 const u16* __restrict__ Vp,
                 u16* __restrict__ Ob) {
    __shared__ u16 Ks[16 * 512];   // 16KB packed K tile
    __shared__ u16 Vs[16 * 512];   // 16KB packed V tile
    __shared__ u16 Ps[4 * 1024];   // 4KB: per-wave P (16x64), XOR-swizzled
    int bid = blockIdx.x;          // 1024 blocks
    int bk = bid & 7, pr = (bid >> 3) & 63, half = bid >> 9;
    int b = bk >> 2, kvh = bk & 3;
    int t = threadIdx.x, lane = t & 63, w = t >> 6, quad = lane >> 4, l16 = lane & 15;
    int l7 = l16 & 7, hi = l16 >> 3;
    int h = kvh * 4 + half * 2 + (w & 1);
    int qt = (w < 2) ? (127 - pr) : pr;
    int nkt = (qt >> 2) + 1;
    int nktL = 32 - (pr >> 2);     // wave-uniform loop bound

    short8 ones;
    #pragma unroll
    for (int j = 0; j < 8; j++) ones[j] = (short)0x3F80;

    // Q fragments (A-layout): RoPE + KSCALE applied in-register (hd pairs are lane-local)
    short8 qf[4];
    {
        int s = qt * 16 + l16;
        const u16* qp = QKV + ((size_t)(b * S_ + s)) * 3072 + h * HD_ + quad * 8;
        const float2* fr2 = (const float2*)freqs;
        #pragma unroll
        for (int c = 0; c < 4; c++) {
            short8 v = *(const short8*)(qp + c * 32);
            short8 o;
            #pragma unroll
            for (int jp = 0; jp < 4; jp++) {
                float2 cs = fr2[s * 64 + c * 16 + quad * 4 + jp];
                float x0 = bf2f((u16)v[2 * jp]), x1 = bf2f((u16)v[2 * jp + 1]);
                o[2 * jp]     = (short)f2bf((x0 * cs.x - x1 * cs.y) * KSCALE);
                o[2 * jp + 1] = (short)f2bf((x0 * cs.y + x1 * cs.x) * KSCALE);
            }
            qf[c] = o;
        }
    }
    float m_i = -3e38f;
    f4 ls = (f4){0.f, 0.f, 0.f, 0.f};
    f4 o[8];
    #pragma unroll
    for (int n = 0; n < 8; n++) o[n] = (f4){0.f, 0.f, 0.f, 0.f};

    const u16* Kpb = Kp + (size_t)bk * 32 * 8192;
    const u16* Vpb = Vp + (size_t)bk * 32 * 8192;
    u16* P = Ps + w * 1024;

    for (int kt = 0; kt < nktL; kt++) {
        // stage packed K,V tiles: wave w stages fragments w*4..w*4+3 of each
        {
            const u16* ks = Kpb + (size_t)kt * 8192 + (w * 4) * 512 + lane * 8;
            const u16* vs = Vpb + (size_t)kt * 8192 + (w * 4) * 512 + lane * 8;
            #pragma unroll
            for (int i = 0; i < 4; i++) {
                GLDS16(ks + i * 512, &Ks[(w * 4 + i) * 512]);
                GLDS16(vs + i * 512, &Vs[(w * 4 + i) * 512]);
            }
        }
        __syncthreads();

        if (kt < nkt) {   // wave-uniform activity guard
            // QK^T (Q pre-scaled -> scores already in log2 domain)
            f4 sc[4];
            #pragma unroll
            for (int n = 0; n < 4; n++) sc[n] = (f4){0.f, 0.f, 0.f, 0.f};
            #pragma unroll
            for (int n = 0; n < 4; n++) {
                #pragma unroll
                for (int c = 0; c < 4; c++) {
                    short8 kf = *(const short8*)&Ks[(n * 4 + c) * 512 + lane * 8];
                    sc[n] = __builtin_amdgcn_mfma_f32_16x16x32_bf16(qf[c], kf, sc[n], 0, 0, 0);
                }
            }
            // causal mask only on the diagonal k-tile
            if (kt == nkt - 1) {
                int qrow0 = qt * 16 + quad * 4;
                #pragma unroll
                for (int n = 0; n < 4; n++) {
                    int colg = kt * 64 + n * 16 + l16;
                    #pragma unroll
                    for (int r = 0; r < 4; r++)
                        sc[n][r] = (colg <= qrow0 + r) ? sc[n][r] : -3e38f;
                }
            }
            // wave-group max (one scalar m per wave; exact — any per-row constant works)
            float gm = fmaxf(fmaxf(sc[0][0], sc[0][1]), fmaxf(sc[0][2], sc[0][3]));
            #pragma unroll
            for (int n = 1; n < 4; n++)
                gm = fmaxf(gm, fmaxf(fmaxf(sc[n][0], sc[n][1]), fmaxf(sc[n][2], sc[n][3])));
            #pragma unroll
            for (int off = 1; off < 64; off <<= 1) gm = fmaxf(gm, __shfl_xor(gm, off, 64));
            float mnew = fmaxf(m_i, gm);
            if (mnew > m_i) {              // wave-uniform branch
                float al = exp2f(m_i - mnew);
                m_i = mnew;
                #pragma unroll
                for (int r = 0; r < 4; r++) ls[r] *= al;
                #pragma unroll
                for (int nt = 0; nt < 8; nt++)
                    #pragma unroll
                    for (int r = 0; r < 4; r++) o[nt][r] *= al;
            }
            // P = exp2(s - m), truncate-pack to bf16, swizzled LDS write
            #pragma unroll
            for (int n = 0; n < 4; n++) {
                #pragma unroll
                for (int r = 0; r < 4; r++) {
                    float p = exp2f(sc[n][r] - m_i);
                    union { float f; unsigned int u; } cv; cv.f = p;
                    int row = quad * 4 + r;
                    int sw = (n * 2 + hi) ^ (row & 7);
                    P[row * 64 + sw * 8 + l7] = (u16)(cv.u >> 16);
                }
            }
            __asm__ volatile("s_waitcnt lgkmcnt(0)" ::: "memory");

            // PV: O += P @ V ; l += P @ ones (MFMA row-sum)
            #pragma unroll
            for (int kc = 0; kc < 2; kc++) {
                short8 af = *(const short8*)&P[l16 * 64 + (((kc * 4 + quad) ^ l7) << 3)];
                ls = __builtin_amdgcn_mfma_f32_16x16x32_bf16(af, ones, ls, 0, 0, 0);
                #pragma unroll
                for (int nt = 0; nt < 8; nt++) {
                    short8 vf = *(const short8*)&Vs[(nt * 2 + kc) * 512 + lane * 8];
                    o[nt] = __builtin_amdgcn_mfma_f32_16x16x32_bf16(af, vf, o[nt], 0, 0, 0);
                }
            }
        }
        __syncthreads();
    }
    // epilogue
    float rl[4];
    #pragma unroll
    for (int r = 0; r < 4; r++) rl[r] = 1.0f / ls[r];
    #pragma unroll
    for (int nt = 0; nt < 8; nt++)
        #pragma unroll
        for (int r = 0; r < 4; r++) {
            size_t row = (size_t)b * S_ + qt * 16 + quad * 4 + r;
            Ob[row * 2048 + h * HD_ + nt * 16 + l16] = f2bf(o[nt][r] * rl[r]);
        }
}

extern "C" void kernel_launch(void* const* d_in, const int* in_sizes, int n_in,
                              void* d_out, int out_size, void* d_ws, size_t ws_size,
                              hipStream_t stream) {
    const float* x     = (const float*)d_in[0];
    const float* freqs = (const float*)d_in[1];
    const float* wq    = (const float*)d_in[2];
    const float* wk    = (const float*)d_in[3];
    const float* wv    = (const float*)d_in[4];
    const float* wo    = (const float*)d_in[5];
    float* out = (float*)d_out;

    char* p = (char*)d_ws;
    u16* xb    = (u16*)p; p += (size_t)4096 * 2048 * 2;   // 16MB
    u16* wqkvb = (u16*)p; p += (size_t)3072 * 2048 * 2;   // 12MB
    u16* wob   = (u16*)p; p += (size_t)2048 * 2048 * 2;   // 8MB
    u16* QKVb  = (u16*)p; p += (size_t)4096 * 3072 * 2;   // 24MB
    u16* Kpb   = (u16*)p; p += (size_t)8 * 32 * 8192 * 2; // 4MB
    u16* Vpb   = (u16*)p; p += (size_t)8 * 32 * 8192 * 2; // 4MB
    u16* attnb = xb;  // reuse: x not needed after QKV GEMM

    cast_all<<<18432, 256, 0, stream>>>(x, wq, wk, wv, wo, xb, wqkvb, wob);

    gemm_bt<true, 24><<<768, 256, 0, stream>>>(xb, wqkvb, QKVb, 4096, 3072, 2048);

    pack_k<<<1024, 256, 0, stream>>>(QKVb, freqs, Kpb);
    pack_v<<<256, 256, 0, stream>>>(QKVb, Vpb);

    attn_kernel<<<1024, 256, 0, stream>>>(QKVb, freqs, Kpb, Vpb, attnb);

    gemm_bt<false, 16><<<512, 256, 0, stream>>>(attnb, wob, out, 4096, 2048, 2048);
}

// Round 10
// 323.071 us; speedup vs baseline: 1.0781x; 1.0104x over previous
//
#include <hip/hip_runtime.h>
#include <stdint.h>

#define B_ 2
#define S_ 2048
#define DIM_ 2048
#define H_ 16
#define KVH_ 4
#define HD_ 128

typedef short short8 __attribute__((ext_vector_type(8)));
typedef float f4 __attribute__((ext_vector_type(4)));
typedef unsigned short u16;

// softmax scale folded into Q at attn load: 1/sqrt(128) * log2(e)
#define KSCALE (0.08838834764831845f * 1.4426950408889634f)

__device__ __forceinline__ float bf2f(u16 u) {
    union { unsigned int i; float f; } c; c.i = ((unsigned int)u) << 16; return c.f;
}
__device__ __forceinline__ u16 f2bf(float f) {
    union { float f; unsigned int i; } c; c.f = f;
    return (u16)((c.i + 0x7fffu + ((c.i >> 16) & 1u)) >> 16);
}

// async global->LDS, 16B per lane; LDS dest is wave-uniform base + lane*16
#define GLDS16(gp, lp) \
    __builtin_amdgcn_global_load_lds((const __attribute__((address_space(1))) unsigned int*)(gp), \
                                     (__attribute__((address_space(3))) unsigned int*)(lp), 16, 0, 0)

// ---------------- fused fp32 -> bf16 cast of all 5 tensors ----------------
__global__ void cast_all(const float* __restrict__ x,  const float* __restrict__ wq,
                         const float* __restrict__ wk, const float* __restrict__ wv,
                         const float* __restrict__ wo,
                         u16* __restrict__ xb, u16* __restrict__ wqkvb, u16* __restrict__ wob) {
    int i = blockIdx.x * 256 + threadIdx.x;   // float4 index, total 4718592
    const float4* src; ushort4* dst; int j;
    if (i < 2097152)      { src = (const float4*)x;  dst = (ushort4*)xb;                 j = i; }
    else if (i < 3145728) { src = (const float4*)wq; dst = (ushort4*)wqkvb;              j = i - 2097152; }
    else if (i < 3407872) { src = (const float4*)wk; dst = (ushort4*)wqkvb + 1048576;    j = i - 3145728; }
    else if (i < 3670016) { src = (const float4*)wv; dst = (ushort4*)wqkvb + 1310720;    j = i - 3407872; }
    else                  { src = (const float4*)wo; dst = (ushort4*)wob;                j = i - 3670016; }
    float4 v = src[j];
    ushort4 o;
    o.x = f2bf(v.x); o.y = f2bf(v.y); o.z = f2bf(v.z); o.w = f2bf(v.w);
    dst[j] = o;
}

// ---------------- GEMM: C[M,N] = A[M,K] @ W[N,K]^T, m97 structure, XCD-swizzled ----------------
template<bool OUT_BF16, int NBX>
__global__ __launch_bounds__(256) void gemm_bt(const u16* __restrict__ A,
                                               const u16* __restrict__ W,
                                               void* __restrict__ Cout,
                                               int M, int N, int K) {
    __shared__ u16 As[128 * 32];
    __shared__ u16 Bs[128 * 32];
    int t = threadIdx.x, lane = t & 63, w = t >> 6;
    int quad = lane >> 4, l16 = lane & 15;
    int wm = w & 1, wn = w >> 1;
    int bid = blockIdx.x;
    int xcd = bid & 7, grp = bid >> 3;
    int bx = grp % NBX, by = (grp / NBX) * 8 + xcd;
    size_t m0 = (size_t)by * 128, n0 = (size_t)bx * 128;

    int c0 = w * 2;
    int ar = c0 * 16 + (lane >> 2);
    int ac = (lane & 3) * 8;
    const u16* Abase = A + (m0 + ar) * (size_t)K + ac;
    const u16* Bbase = W + (n0 + ar) * (size_t)K + ac;
    u16* Adst = As + c0 * 512;
    u16* Bdst = Bs + c0 * 512;

    f4 acc[4][4];
    #pragma unroll
    for (int i = 0; i < 4; i++)
        #pragma unroll
        for (int j = 0; j < 4; j++) acc[i][j] = (f4){0.f, 0.f, 0.f, 0.f};

    int nk = K >> 5;
    for (int kt = 0; kt < nk; kt++) {
        const u16* ga = Abase + kt * 32;
        const u16* gb = Bbase + kt * 32;
        GLDS16(ga, Adst);
        GLDS16(ga + 16 * (size_t)K, Adst + 512);
        GLDS16(gb, Bdst);
        GLDS16(gb + 16 * (size_t)K, Bdst + 512);
        __syncthreads();
        short8 a[4], b[4];
        #pragma unroll
        for (int i = 0; i < 4; i++) a[i] = *(const short8*)&As[(wm * 64 + i * 16 + l16) * 32 + quad * 8];
        #pragma unroll
        for (int j = 0; j < 4; j++) b[j] = *(const short8*)&Bs[(wn * 64 + j * 16 + l16) * 32 + quad * 8];
        #pragma unroll
        for (int i = 0; i < 4; i++)
            #pragma unroll
            for (int j = 0; j < 4; j++)
                acc[i][j] = __builtin_amdgcn_mfma_f32_16x16x32_bf16(a[i], b[j], acc[i][j], 0, 0, 0);
        __syncthreads();
    }
    #pragma unroll
    for (int i = 0; i < 4; i++) {
        size_t row = m0 + wm * 64 + i * 16 + quad * 4;
        #pragma unroll
        for (int j = 0; j < 4; j++) {
            size_t col = n0 + wn * 64 + j * 16 + l16;
            #pragma unroll
            for (int r = 0; r < 4; r++) {
                if (OUT_BF16) ((u16*)Cout)[(row + r) * N + col] = f2bf(acc[i][j][r]);
                else          ((float*)Cout)[(row + r) * N + col] = acc[i][j][r];
            }
        }
    }
}

// ---------------- pack K (with fused RoPE) into MFMA B-fragment order ----------------
__global__ __launch_bounds__(256) void pack_k(const u16* __restrict__ QKV,
                                              const float* __restrict__ freqs,
                                              u16* __restrict__ Kp) {
    int gid = blockIdx.x * 256 + threadIdx.x;   // 262144
    int lane = gid & 63;
    int fid = (gid >> 6) & 15;
    int kt = (gid >> 10) & 31;
    int bk = gid >> 15;
    int b = bk >> 2, kvh = bk & 3;
    int n = fid >> 2, c = fid & 3;
    int l16 = lane & 15, quad = lane >> 4;
    int s = kt * 64 + n * 16 + l16;
    const u16* src = QKV + (size_t)(b * 2048 + s) * 3072 + 2048 + kvh * 128 + c * 32 + quad * 8;
    short8 v = *(const short8*)src;
    short8 o;
    #pragma unroll
    for (int jp = 0; jp < 4; jp++) {
        int hd2 = c * 16 + quad * 4 + jp;
        float2 cw = ((const float2*)freqs)[s * 64 + hd2];
        float x0 = bf2f((u16)v[2 * jp]), x1 = bf2f((u16)v[2 * jp + 1]);
        o[2 * jp]     = (short)f2bf(x0 * cw.x - x1 * cw.y);
        o[2 * jp + 1] = (short)f2bf(x0 * cw.y + x1 * cw.x);
    }
    *(short8*)&Kp[(size_t)gid * 8] = o;
}

// ---------------- pack V into MFMA B-fragment order (LDS-tile transpose) ----------------
__global__ __launch_bounds__(256) void pack_v(const u16* __restrict__ QKV, u16* __restrict__ Vp) {
    __shared__ u16 L[64 * 136];
    int bid = blockIdx.x;          // 256 blocks
    int bk = bid & 7, kt = bid >> 3;
    int b = bk >> 2, kvh = bk & 3;
    int t = threadIdx.x;
    const u16* src = QKV + (size_t)(b * 2048 + kt * 64) * 3072 + 2560 + kvh * 128;
    #pragma unroll
    for (int it = 0; it < 4; it++) {
        int idx = t + it * 256;
        int r = idx >> 4, c = idx & 15;
        *(short8*)&L[r * 136 + c * 8] = *(const short8*)(src + (size_t)r * 3072 + c * 8);
    }
    __syncthreads();
    u16* dst = Vp + ((size_t)bk * 32 + kt) * 8192;
    #pragma unroll
    for (int it = 0; it < 4; it++) {
        int idx = t + it * 256;
        int fid = idx >> 6, lane = idx & 63;
        int nt = fid >> 1, kc = fid & 1;
        int l16 = lane & 15, quad = lane >> 4;
        int hd = nt * 16 + l16;
        int s0 = kc * 32 + quad * 8;
        short8 v;
        #pragma unroll
        for (int j = 0; j < 8; j++) v[j] = (short)L[(s0 + j) * 136 + hd];
        *(short8*)&dst[(size_t)idx * 8] = v;
    }
}

// ---------------- Flash attention: R7 sequential-phase + double-buffered staging ----------------
// block = (bk, pr): 4 waves = 4 GQA heads, q-tile 127-pr then pr sequentially (zero wave
// idle). K/V double-buffered: prefetch tile kt+1 while computing kt; the single barrier
// per iteration waits on a load issued a full iteration earlier. LDS 72KB -> 2 blocks/CU
// (grid 512 = 2/CU anyway, so dbuf is free). RoPE-Q fused at fragment load.
__global__ __launch_bounds__(256) __attribute__((amdgpu_waves_per_eu(2, 2)))
void attn_kernel(const u16* __restrict__ QKV,
                 const float* __restrict__ freqs,
                 const u16* __restrict__ Kp,
                 const u16* __restrict__ Vp,
                 u16* __restrict__ Ob) {
    __shared__ u16 Ks[2][8192];    // 2 x 16KB packed K tile
    __shared__ u16 Vs[2][8192];    // 2 x 16KB packed V tile
    __shared__ u16 Ps[4 * 1024];   // 8KB: per-wave P (16x64), XOR-swizzled
    int bid = blockIdx.x;          // 512 blocks
    int bk = bid & 7, pr = bid >> 3;   // pr in [0,64)
    int b = bk >> 2, kvh = bk & 3;
    int t = threadIdx.x, lane = t & 63, w = t >> 6, quad = lane >> 4, l16 = lane & 15;
    int l7 = l16 & 7, hi = l16 >> 3;
    int h = kvh * 4 + w;

    short8 ones;
    #pragma unroll
    for (int j = 0; j < 8; j++) ones[j] = (short)0x3F80;

    const u16* Kpb = Kp + (size_t)bk * 32 * 8192;
    const u16* Vpb = Vp + (size_t)bk * 32 * 8192;
    u16* P = Ps + w * 1024;

    for (int ph = 0; ph < 2; ph++) {
        int qt = ph ? pr : 127 - pr;
        int nkt = (qt >> 2) + 1;

        // Q fragments (A-layout): RoPE + KSCALE applied in-register (hd pairs lane-local)
        short8 qf[4];
        {
            int s = qt * 16 + l16;
            const u16* qp = QKV + ((size_t)(b * S_ + s)) * 3072 + h * HD_ + quad * 8;
            const float2* fr2 = (const float2*)freqs;
            #pragma unroll
            for (int c = 0; c < 4; c++) {
                short8 v = *(const short8*)(qp + c * 32);
                short8 o;
                #pragma unroll
                for (int jp = 0; jp < 4; jp++) {
                    float2 cs = fr2[s * 64 + c * 16 + quad * 4 + jp];
                    float x0 = bf2f((u16)v[2 * jp]), x1 = bf2f((u16)v[2 * jp + 1]);
                    o[2 * jp]     = (short)f2bf((x0 * cs.x - x1 * cs.y) * KSCALE);
                    o[2 * jp + 1] = (short)f2bf((x0 * cs.y + x1 * cs.x) * KSCALE);
                }
                qf[c] = o;
            }
        }
        float m_i = -3e38f;
        f4 ls = (f4){0.f, 0.f, 0.f, 0.f};
        f4 o[8];
        #pragma unroll
        for (int n = 0; n < 8; n++) o[n] = (f4){0.f, 0.f, 0.f, 0.f};

        // initial stage of tile 0 into buffer 0 (wave w stages fragments w*4..w*4+3)
        {
            const u16* ks = Kpb + (w * 4) * 512 + lane * 8;
            const u16* vs = Vpb + (w * 4) * 512 + lane * 8;
            #pragma unroll
            for (int i = 0; i < 4; i++) {
                GLDS16(ks + i * 512, &Ks[0][(w * 4 + i) * 512]);
                GLDS16(vs + i * 512, &Vs[0][(w * 4 + i) * 512]);
            }
        }

        for (int kt = 0; kt < nkt; kt++) {
            int buf = kt & 1;
            __syncthreads();   // drains the stage of tile kt (issued one iteration ago)
            if (kt + 1 < nkt) {        // prefetch tile kt+1 into the other buffer
                int nb = buf ^ 1;
                const u16* ks = Kpb + (size_t)(kt + 1) * 8192 + (w * 4) * 512 + lane * 8;
                const u16* vs = Vpb + (size_t)(kt + 1) * 8192 + (w * 4) * 512 + lane * 8;
                #pragma unroll
                for (int i = 0; i < 4; i++) {
                    GLDS16(ks + i * 512, &Ks[nb][(w * 4 + i) * 512]);
                    GLDS16(vs + i * 512, &Vs[nb][(w * 4 + i) * 512]);
                }
            }

            // QK^T (Q pre-scaled -> scores already in log2 domain)
            f4 sc[4];
            #pragma unroll
            for (int n = 0; n < 4; n++) sc[n] = (f4){0.f, 0.f, 0.f, 0.f};
            #pragma unroll
            for (int n = 0; n < 4; n++) {
                #pragma unroll
                for (int c = 0; c < 4; c++) {
                    short8 kf = *(const short8*)&Ks[buf][(n * 4 + c) * 512 + lane * 8];
                    sc[n] = __builtin_amdgcn_mfma_f32_16x16x32_bf16(qf[c], kf, sc[n], 0, 0, 0);
                }
            }
            // causal mask only on the diagonal k-tile
            if (kt == nkt - 1) {
                int qrow0 = qt * 16 + quad * 4;
                #pragma unroll
                for (int n = 0; n < 4; n++) {
                    int colg = kt * 64 + n * 16 + l16;
                    #pragma unroll
                    for (int r = 0; r < 4; r++)
                        sc[n][r] = (colg <= qrow0 + r) ? sc[n][r] : -3e38f;
                }
            }
            // wave-group max (one scalar m per wave; exact — any per-row constant works)
            float gm = fmaxf(fmaxf(sc[0][0], sc[0][1]), fmaxf(sc[0][2], sc[0][3]));
            #pragma unroll
            for (int n = 1; n < 4; n++)
                gm = fmaxf(gm, fmaxf(fmaxf(sc[n][0], sc[n][1]), fmaxf(sc[n][2], sc[n][3])));
            #pragma unroll
            for (int off = 1; off < 64; off <<= 1) gm = fmaxf(gm, __shfl_xor(gm, off, 64));
            float mnew = fmaxf(m_i, gm);
            if (mnew > m_i) {              // wave-uniform branch
                float al = exp2f(m_i - mnew);
                m_i = mnew;
                #pragma unroll
                for (int r = 0; r < 4; r++) ls[r] *= al;
                #pragma unroll
                for (int nt = 0; nt < 8; nt++)
                    #pragma unroll
                    for (int r = 0; r < 4; r++) o[nt][r] *= al;
            }
            // P = exp2(s - m), truncate-pack to bf16, swizzled LDS write (per-wave region)
            #pragma unroll
            for (int n = 0; n < 4; n++) {
                #pragma unroll
                for (int r = 0; r < 4; r++) {
                    float p = exp2f(sc[n][r] - m_i);
                    union { float f; unsigned int u; } cv; cv.f = p;
                    int row = quad * 4 + r;
                    int sw = (n * 2 + hi) ^ (row & 7);
                    P[row * 64 + sw * 8 + l7] = (u16)(cv.u >> 16);
                }
            }
            __asm__ volatile("s_waitcnt lgkmcnt(0)" ::: "memory");

            // PV: O += P @ V ; l += P @ ones (MFMA row-sum)
            #pragma unroll
            for (int kc = 0; kc < 2; kc++) {
                short8 af = *(const short8*)&P[l16 * 64 + (((kc * 4 + quad) ^ l7) << 3)];
                ls = __builtin_amdgcn_mfma_f32_16x16x32_bf16(af, ones, ls, 0, 0, 0);
                #pragma unroll
                for (int nt = 0; nt < 8; nt++) {
                    short8 vf = *(const short8*)&Vs[buf][(nt * 2 + kc) * 512 + lane * 8];
                    o[nt] = __builtin_amdgcn_mfma_f32_16x16x32_bf16(af, vf, o[nt], 0, 0, 0);
                }
            }
        }
        // epilogue for this q-tile
        float rl[4];
        #pragma unroll
        for (int r = 0; r < 4; r++) rl[r] = 1.0f / ls[r];
        #pragma unroll
        for (int nt = 0; nt < 8; nt++)
            #pragma unroll
            for (int r = 0; r < 4; r++) {
                size_t row = (size_t)b * S_ + qt * 16 + quad * 4 + r;
                Ob[row * 2048 + h * HD_ + nt * 16 + l16] = f2bf(o[nt][r] * rl[r]);
            }
        __syncthreads();   // protect buffers before next phase's initial stage
    }
}

extern "C" void kernel_launch(void* const* d_in, const int* in_sizes, int n_in,
                              void* d_out, int out_size, void* d_ws, size_t ws_size,
                              hipStream_t stream) {
    const float* x     = (const float*)d_in[0];
    const float* freqs = (const float*)d_in[1];
    const float* wq    = (const float*)d_in[2];
    const float* wk    = (const float*)d_in[3];
    const float* wv    = (const float*)d_in[4];
    const float* wo    = (const float*)d_in[5];
    float* out = (float*)d_out;

    char* p = (char*)d_ws;
    u16* xb    = (u16*)p; p += (size_t)4096 * 2048 * 2;   // 16MB
    u16* wqkvb = (u16*)p; p += (size_t)3072 * 2048 * 2;   // 12MB
    u16* wob   = (u16*)p; p += (size_t)2048 * 2048 * 2;   // 8MB
    u16* QKVb  = (u16*)p; p += (size_t)4096 * 3072 * 2;   // 24MB
    u16* Kpb   = (u16*)p; p += (size_t)8 * 32 * 8192 * 2; // 4MB
    u16* Vpb   = (u16*)p; p += (size_t)8 * 32 * 8192 * 2; // 4MB
    u16* attnb = xb;  // reuse: x not needed after QKV GEMM

    cast_all<<<18432, 256, 0, stream>>>(x, wq, wk, wv, wo, xb, wqkvb, wob);

    gemm_bt<true, 24><<<768, 256, 0, stream>>>(xb, wqkvb, QKVb, 4096, 3072, 2048);

    pack_k<<<1024, 256, 0, stream>>>(QKVb, freqs, Kpb);
    pack_v<<<256, 256, 0, stream>>>(QKVb, Vpb);

    attn_kernel<<<512, 256, 0, stream>>>(QKVb, freqs, Kpb, Vpb, attnb);

    gemm_bt<false, 16><<<512, 256, 0, stream>>>(attnb, wob, out, 4096, 2048, 2048);
}